// Round 2
// baseline (253.994 us; speedup 1.0000x reference)
//
#include <hip/hip_runtime.h>

// SuperDCFrontShareLayer — complex Givens-like pair transform.
// Harness path observed (rocprof + absmax=0.0): REAL-ONLY output
// (out_size = rows*1024 floats). In that representation the op degenerates
// to a per-column scale:  out[r][c] = s[c] * x[r][c],
//         s[c] = w[(c-1)>>1] for 1 <= c <= 2n, else 1.0.
//
// R1 lesson: a single-float4-in-flight grid-stride loop (VGPR=8) is
// LATENCY/MLP-bound at 2.45 TB/s HBM — the compiler serializes
// load -> waitcnt -> store on the same registers. Fix:
//   * 8x manual unroll, disjoint registers: 8 loads in flight per wave.
//   * non-temporal stores: out is never re-read; don't let the write
//     stream evict x from the 256 MB L3 (FETCH was exactly x/2).
// Column-group (tid & 255) is grid-stride-invariant (stride % 256 == 0),
// so the 4 per-thread weights are computed once.

#define COLS   1024
#define C4     (COLS / 4)    // 256 float4 per row
#define TPB    256
#define UNROLL 8

typedef float v4f __attribute__((ext_vector_type(4)));

__global__ __launch_bounds__(TPB) void sdc_scale4(
    const v4f* __restrict__ x4, const float* __restrict__ w,
    v4f* __restrict__ out4, int n, long long total4)
{
    const long long tid = (long long)blockIdx.x * TPB + threadIdx.x;
    const long long S   = (long long)gridDim.x * TPB;   // multiple of C4

    // Per-thread column group -> 4 weights, loaded once (w is 2 KB, L1-hot).
    const int c0  = (int)(tid & (C4 - 1)) * 4;
    const int lim = 2 * n;                               // active cols [1, 2n]
    const float s0 = (c0 >= 1 && c0     <= lim) ? w[(c0 - 1) >> 1] : 1.0f;
    const float s1 = (             c0 + 1 <= lim) ? w[(c0    ) >> 1] : 1.0f;
    const float s2 = (             c0 + 2 <= lim) ? w[(c0 + 1) >> 1] : 1.0f;
    const float s3 = (             c0 + 3 <= lim) ? w[(c0 + 2) >> 1] : 1.0f;
    const v4f sv = {s0, s1, s2, s3};

    if (tid + (long long)(UNROLL - 1) * S < total4) {
        // Fast path: 8 independent loads in flight, then muls, then nt stores.
        v4f v0 = x4[tid + 0 * S];
        v4f v1 = x4[tid + 1 * S];
        v4f v2 = x4[tid + 2 * S];
        v4f v3 = x4[tid + 3 * S];
        v4f v4 = x4[tid + 4 * S];
        v4f v5 = x4[tid + 5 * S];
        v4f v6 = x4[tid + 6 * S];
        v4f v7 = x4[tid + 7 * S];
        v0 *= sv; v1 *= sv; v2 *= sv; v3 *= sv;
        v4 *= sv; v5 *= sv; v6 *= sv; v7 *= sv;
        __builtin_nontemporal_store(v0, &out4[tid + 0 * S]);
        __builtin_nontemporal_store(v1, &out4[tid + 1 * S]);
        __builtin_nontemporal_store(v2, &out4[tid + 2 * S]);
        __builtin_nontemporal_store(v3, &out4[tid + 3 * S]);
        __builtin_nontemporal_store(v4, &out4[tid + 4 * S]);
        __builtin_nontemporal_store(v5, &out4[tid + 5 * S]);
        __builtin_nontemporal_store(v6, &out4[tid + 6 * S]);
        __builtin_nontemporal_store(v7, &out4[tid + 7 * S]);
    } else {
        for (long long i = tid; i < total4; i += S) {
            v4f v = x4[i];
            v *= sv;
            __builtin_nontemporal_store(v, &out4[i]);
        }
    }
}

// Interleaved-complex fallback (unused by observed harness, kept correct).
__global__ __launch_bounds__(TPB) void sdc_interleaved(
    const float* __restrict__ x, const float* __restrict__ w,
    float* __restrict__ out, int n)
{
    const int idx = blockIdx.x * TPB + threadIdx.x;
    const int row = idx >> 9;            // 512 pair-threads per row
    const int t   = idx & 511;

    const float* xr   = x   + (size_t)row * COLS;
    float*       orow = out + (size_t)row * (2 * COLS);

    const int a = 2 * t + 1;
    const int b = a + 1;
    const float xa = xr[a];

    if (t < n) {
        const float xb = xr[b];
        const float tj = w[t];
        const float kj = sqrtf(1.0f - tj * tj + 1e-6f);
        *(float2*)(orow + 2 * a) = make_float2(tj * xa, kj * xb);
        *(float2*)(orow + 2 * b) = make_float2(tj * xb, kj * xa);
    } else {
        *(float2*)(orow + 2 * a) = make_float2(xa, 0.0f);
        if (b < COLS)
            *(float2*)(orow + 2 * b) = make_float2(xr[b], 0.0f);
    }
    if (t == 0)
        *(float2*)orow = make_float2(xr[0], 0.0f);
}

extern "C" void kernel_launch(void* const* d_in, const int* in_sizes, int n_in,
                              void* d_out, int out_size, void* d_ws, size_t ws_size,
                              hipStream_t stream) {
    const float* x   = (const float*)d_in[0];
    const float* w   = (const float*)d_in[1];
    float*       out = (float*)d_out;

    const int rows = in_sizes[0] / COLS;   // 32768
    const int n    = in_sizes[1];          // 511 == sample_arch

    if (out_size >= rows * 2 * COLS) {
        const int blocks = (rows * 512) / TPB;
        sdc_interleaved<<<blocks, TPB, 0, stream>>>(x, w, out, n);
    } else {
        const long long total4 = (long long)rows * C4;   // 8,388,608
        const long long elems  = (long long)TPB * UNROLL;
        const int blocks = (int)((total4 + elems - 1) / elems);   // 4096
        sdc_scale4<<<blocks, TPB, 0, stream>>>(
            (const v4f*)x, w, (v4f*)out, n, total4);
    }
}

// Round 3
// 237.791 us; speedup vs baseline: 1.0681x; 1.0681x over previous
//
#include <hip/hip_runtime.h>

// SuperDCFrontShareLayer — degenerates (real-only harness path) to
//   out[r][c] = s[c] * x[r][c],  s[c] = w[(c-1)>>1] for 1<=c<=2n else 1.0
//
// R1: single load in flight (VGPR=8) -> 2.45 TB/s, latency-serialized.
// R2: 8-deep unroll + nontemporal stores -> 1.86 TB/s. FETCH unchanged ->
//     nt stores did NOT improve L3 residency, they just slowed the write
//     path ~30%. Lesson: NO nt stores on gfx950 streaming writes.
// R3: keep the 8-deep MLP, drop nt, and make each block's 8 slices
//     block-contiguous (32 KB/chunk, slices 4 KB apart) for DRAM/L2
//     locality. Regular stores (the harness fill kernel proves normal
//     stores sustain 6.6 TB/s).

#define COLS   1024
#define C4     (COLS / 4)    // 256 float4 per row
#define TPB    256
#define UNROLL 8
#define GRID_BLOCKS 2048

typedef float v4f __attribute__((ext_vector_type(4)));

__global__ __launch_bounds__(TPB) void sdc_scale4(
    const v4f* __restrict__ x4, const float* __restrict__ w,
    v4f* __restrict__ out4, int n, long long total4)
{
    const int  lane = threadIdx.x;
    // Chunk layout: idx = base + k*TPB + lane. TPB % C4 == 0 and every
    // base is a multiple of TPB*UNROLL, so (idx mod C4) == (lane mod C4)
    // for ALL k and all iterations -> per-thread weights are loop-invariant.
    const int c0  = (lane & (C4 - 1)) * 4;
    const int lim = 2 * n;                         // active cols [1, 2n]
    const float s0 = (c0 >= 1 && c0 <= lim) ? w[(c0 - 1) >> 1] : 1.0f;
    const float s1 = (c0 + 1 <= lim)        ? w[(c0    ) >> 1] : 1.0f;
    const float s2 = (c0 + 2 <= lim)        ? w[(c0 + 1) >> 1] : 1.0f;
    const float s3 = (c0 + 3 <= lim)        ? w[(c0 + 2) >> 1] : 1.0f;
    const v4f sv = {s0, s1, s2, s3};

    const long long chunk  = (long long)TPB * UNROLL;          // 2048 float4
    const long long stride = (long long)gridDim.x * chunk;
    long long base = (long long)blockIdx.x * chunk + lane;

    // Fast path: full 8-slice chunks. 8 independent loads in flight,
    // then 8 muls, then 8 regular stores.
    for (; base + (long long)(UNROLL - 1) * TPB < total4; base += stride) {
        v4f v0 = x4[base + 0 * TPB];
        v4f v1 = x4[base + 1 * TPB];
        v4f v2 = x4[base + 2 * TPB];
        v4f v3 = x4[base + 3 * TPB];
        v4f v4 = x4[base + 4 * TPB];
        v4f v5 = x4[base + 5 * TPB];
        v4f v6 = x4[base + 6 * TPB];
        v4f v7 = x4[base + 7 * TPB];
        v0 *= sv; v1 *= sv; v2 *= sv; v3 *= sv;
        v4 *= sv; v5 *= sv; v6 *= sv; v7 *= sv;
        out4[base + 0 * TPB] = v0;
        out4[base + 1 * TPB] = v1;
        out4[base + 2 * TPB] = v2;
        out4[base + 3 * TPB] = v3;
        out4[base + 4 * TPB] = v4;
        out4[base + 5 * TPB] = v5;
        out4[base + 6 * TPB] = v6;
        out4[base + 7 * TPB] = v7;
    }
    // Tail (not taken for 32768x1024, kept for generality).
    for (; base < total4; base += TPB) {
        v4f v = x4[base];
        out4[base] = v * sv;
    }
}

// Interleaved-complex fallback (unused by observed harness, kept correct).
__global__ __launch_bounds__(TPB) void sdc_interleaved(
    const float* __restrict__ x, const float* __restrict__ w,
    float* __restrict__ out, int n)
{
    const int idx = blockIdx.x * TPB + threadIdx.x;
    const int row = idx >> 9;            // 512 pair-threads per row
    const int t   = idx & 511;

    const float* xr   = x   + (size_t)row * COLS;
    float*       orow = out + (size_t)row * (2 * COLS);

    const int a = 2 * t + 1;
    const int b = a + 1;
    const float xa = xr[a];

    if (t < n) {
        const float xb = xr[b];
        const float tj = w[t];
        const float kj = sqrtf(1.0f - tj * tj + 1e-6f);
        *(float2*)(orow + 2 * a) = make_float2(tj * xa, kj * xb);
        *(float2*)(orow + 2 * b) = make_float2(tj * xb, kj * xa);
    } else {
        *(float2*)(orow + 2 * a) = make_float2(xa, 0.0f);
        if (b < COLS)
            *(float2*)(orow + 2 * b) = make_float2(xr[b], 0.0f);
    }
    if (t == 0)
        *(float2*)orow = make_float2(xr[0], 0.0f);
}

extern "C" void kernel_launch(void* const* d_in, const int* in_sizes, int n_in,
                              void* d_out, int out_size, void* d_ws, size_t ws_size,
                              hipStream_t stream) {
    const float* x   = (const float*)d_in[0];
    const float* w   = (const float*)d_in[1];
    float*       out = (float*)d_out;

    const int rows = in_sizes[0] / COLS;   // 32768
    const int n    = in_sizes[1];          // 511 == sample_arch

    if (out_size >= rows * 2 * COLS) {
        const int blocks = (rows * 512) / TPB;
        sdc_interleaved<<<blocks, TPB, 0, stream>>>(x, w, out, n);
    } else {
        const long long total4 = (long long)rows * C4;   // 8,388,608
        sdc_scale4<<<GRID_BLOCKS, TPB, 0, stream>>>(
            (const v4f*)x, w, (v4f*)out, n, total4);
    }
}

// Round 4
// 233.739 us; speedup vs baseline: 1.0867x; 1.0173x over previous
//
#include <hip/hip_runtime.h>
#include <stdint.h>

// SuperDCFrontShareLayer — real-only harness path degenerates to
//   out[r][c] = s[c] * x[r][c],  s[c] = w[(c-1)>>1] for 1<=c<=2n else 1.0
//
// R0/R1/R3: scalar no-loop, float4 grid-stride, float4 8-MLP-contiguous all
// land 77-82 µs (~3.4 TB/s logical) — shape-invariant. Writes are proven
// fast (fills: 6.6 TB/s), window is clean (WRITE_SIZE == own bytes), so the
// READ path is capped at ~half the m13 copy read rate. R4 is a 4-way
// mechanism probe, quarter of the rows each (rocprof splits per dispatch):
//   A: plain no-loop float4 (control, + XCD-chunk swizzle)
//   B: sc0 (L1/TCP-bypass) loads — tests per-CU read-queue depth cap
//   C: nontemporal loads — tests L3 allocate/hit-path drag
//   D: global_load_lds DMA staging — tests the alternate read queue

#define COLS 1024
#define C4   256
#define TPB  256

typedef float v4f __attribute__((ext_vector_type(4)));

__device__ __forceinline__ v4f weights_for(const float* __restrict__ w, int c0, int lim) {
    v4f s;
    s.x = (c0 >= 1 && c0 <= lim) ? w[(c0 - 1) >> 1] : 1.0f;
    s.y = (c0 + 1 <= lim) ? w[(c0    ) >> 1] : 1.0f;
    s.z = (c0 + 2 <= lim) ? w[(c0 + 1) >> 1] : 1.0f;
    s.w = (c0 + 3 <= lim) ? w[(c0 + 2) >> 1] : 1.0f;
    return s;
}

__device__ __forceinline__ int xcd_swz(int bid, int nper) {
    return (bid & 7) * nper + (bid >> 3);   // contiguous 1/8 per XCD; needs grid%8==0
}

// ---- A: plain no-loop float4 ------------------------------------------------
__global__ __launch_bounds__(TPB) void sdc_a_plain(
    const v4f* __restrict__ x4, const float* __restrict__ w,
    v4f* __restrict__ out4, int n, long long base4, int nper)
{
    const int swz = xcd_swz(blockIdx.x, nper);
    const long long i = base4 + (long long)swz * TPB + threadIdx.x;
    const v4f s = weights_for(w, (int)(threadIdx.x & (C4 - 1)) * 4, 2 * n);
    v4f v = x4[i];
    v *= s;
    out4[i] = v;
}

// ---- B: sc0 (L1-bypass scope) load -----------------------------------------
__global__ __launch_bounds__(TPB) void sdc_b_sc0(
    const v4f* __restrict__ x4, const float* __restrict__ w,
    v4f* __restrict__ out4, int n, long long base4, int nper)
{
    const int swz = xcd_swz(blockIdx.x, nper);
    const long long i = base4 + (long long)swz * TPB + threadIdx.x;
    const v4f s = weights_for(w, (int)(threadIdx.x & (C4 - 1)) * 4, 2 * n);
    const v4f* p = x4 + i;
    v4f v;
    asm volatile("global_load_dwordx4 %0, %1, off sc0\n\t"
                 "s_waitcnt vmcnt(0)"
                 : "=v"(v) : "v"(p) : "memory");
    v *= s;
    out4[i] = v;
}

// ---- C: nontemporal (no-L3-allocate) load ----------------------------------
__global__ __launch_bounds__(TPB) void sdc_c_nt(
    const v4f* __restrict__ x4, const float* __restrict__ w,
    v4f* __restrict__ out4, int n, long long base4, int nper)
{
    const int swz = xcd_swz(blockIdx.x, nper);
    const long long i = base4 + (long long)swz * TPB + threadIdx.x;
    const v4f s = weights_for(w, (int)(threadIdx.x & (C4 - 1)) * 4, 2 * n);
    v4f v = __builtin_nontemporal_load(x4 + i);
    v *= s;
    out4[i] = v;   // regular store (R2: nt stores are a 30% regression)
}

// ---- D: global_load_lds DMA staging, 16 KB/block single-shot ---------------
__global__ __launch_bounds__(TPB) void sdc_d_gll(
    const float* __restrict__ x, const float* __restrict__ w,
    float* __restrict__ out, int n, long long base4, int nper)
{
    __shared__ float lds[4096];                    // 16 KB
    const int swz = xcd_swz(blockIdx.x, nper);
    const long long chunk4 = base4 + (long long)swz * 1024;  // 1024 float4 = 16 KB
    const int wave = threadIdx.x >> 6;
    const int lane = threadIdx.x & 63;

    const float* gbase = x + chunk4 * 4;
    // Each wave stages 4 consecutive 1 KB slices: LDS dest is wave-uniform
    // base + lane*16 (HW rule); global src is per-lane. Layout stays linear.
    #pragma unroll
    for (int k = 0; k < 4; ++k) {
        const int j = wave * 4 + k;                 // slice 0..15
        const float* gp = gbase + j * 256 + lane * 4;
        float* lp = &lds[j * 256];                  // wave-uniform
        __builtin_amdgcn_global_load_lds(
            (const __attribute__((address_space(1))) uint32_t*)gp,
            (__attribute__((address_space(3))) uint32_t*)lp,
            16, 0, 0);
    }
    __syncthreads();   // compiler emits s_waitcnt vmcnt(0) lgkmcnt(0) first

    const v4f s = weights_for(w, (int)(threadIdx.x & (C4 - 1)) * 4, 2 * n);
    #pragma unroll
    for (int k = 0; k < 4; ++k) {
        const long long i4 = chunk4 + k * 256 + threadIdx.x;
        v4f v = *(const v4f*)&lds[(k * 256 + threadIdx.x) * 4];
        v *= s;
        *(v4f*)(out + i4 * 4) = v;
    }
}

// ---- fallback: grid-stride float4 (any size) -------------------------------
__global__ __launch_bounds__(TPB) void sdc_fallback(
    const v4f* __restrict__ x4, const float* __restrict__ w,
    v4f* __restrict__ out4, int n, long long total4)
{
    const long long tid = (long long)blockIdx.x * TPB + threadIdx.x;
    const long long S   = (long long)gridDim.x * TPB;
    const v4f s = weights_for(w, (int)(tid & (C4 - 1)) * 4, 2 * n);
    for (long long i = tid; i < total4; i += S) {
        v4f v = x4[i];
        v *= s;
        out4[i] = v;
    }
}

// ---- interleaved-complex fallback (unused by observed harness) -------------
__global__ __launch_bounds__(TPB) void sdc_interleaved(
    const float* __restrict__ x, const float* __restrict__ w,
    float* __restrict__ out, int n)
{
    const int idx = blockIdx.x * TPB + threadIdx.x;
    const int row = idx >> 9;
    const int t   = idx & 511;

    const float* xr   = x   + (size_t)row * COLS;
    float*       orow = out + (size_t)row * (2 * COLS);

    const int a = 2 * t + 1;
    const int b = a + 1;
    const float xa = xr[a];

    if (t < n) {
        const float xb = xr[b];
        const float tj = w[t];
        const float kj = sqrtf(1.0f - tj * tj + 1e-6f);
        *(float2*)(orow + 2 * a) = make_float2(tj * xa, kj * xb);
        *(float2*)(orow + 2 * b) = make_float2(tj * xb, kj * xa);
    } else {
        *(float2*)(orow + 2 * a) = make_float2(xa, 0.0f);
        if (b < COLS)
            *(float2*)(orow + 2 * b) = make_float2(xr[b], 0.0f);
    }
    if (t == 0)
        *(float2*)orow = make_float2(xr[0], 0.0f);
}

extern "C" void kernel_launch(void* const* d_in, const int* in_sizes, int n_in,
                              void* d_out, int out_size, void* d_ws, size_t ws_size,
                              hipStream_t stream) {
    const float* x   = (const float*)d_in[0];
    const float* w   = (const float*)d_in[1];
    float*       out = (float*)d_out;

    const int rows = in_sizes[0] / COLS;   // 32768
    const int n    = in_sizes[1];          // 511 == sample_arch

    if (out_size >= rows * 2 * COLS) {
        const int blocks = (rows * 512) / TPB;
        sdc_interleaved<<<blocks, TPB, 0, stream>>>(x, w, out, n);
        return;
    }

    const long long total4 = (long long)rows * C4;   // 8,388,608
    const long long q4     = total4 / 4;             // 2,097,152

    // Quarter split needs: q4 % TPB == 0 (A/B/C grids), q4 % 1024 == 0 (D
    // chunks), and each grid % 8 == 0 (swizzle). Holds for 32768x1024.
    const long long abc_blk = q4 / TPB;              // 8192
    const long long d_blk   = q4 / 1024;             // 2048
    if ((q4 % 1024) || (abc_blk & 7) || (d_blk & 7)) {
        sdc_fallback<<<2048, TPB, 0, stream>>>((const v4f*)x, w, (v4f*)out, n, total4);
        return;
    }

    sdc_a_plain<<<(int)abc_blk, TPB, 0, stream>>>((const v4f*)x, w, (v4f*)out, n, 0 * q4, (int)(abc_blk / 8));
    sdc_b_sc0 <<<(int)abc_blk, TPB, 0, stream>>>((const v4f*)x, w, (v4f*)out, n, 1 * q4, (int)(abc_blk / 8));
    sdc_c_nt  <<<(int)abc_blk, TPB, 0, stream>>>((const v4f*)x, w, (v4f*)out, n, 2 * q4, (int)(abc_blk / 8));
    sdc_d_gll <<<(int)d_blk,   TPB, 0, stream>>>(x, w, out, n, 3 * q4, (int)(d_blk / 8));
}